// Round 1
// 67.428 us; speedup vs baseline: 1.0951x; 1.0951x over previous
//
#include <hip/hip_runtime.h>

// Problem constants (fixed by setup_inputs): N=65536 tokens, K=8, E=64 experts.
#define TOTAL   524288            // N*K flattened assignments
#define NEXP    64
#define TOPK    8
#define GSIZE   256               // blocks (1 per CU)
#define BLOCK   1024              // threads = 16 waves  -> 4 waves/SIMD
#define NWAVE   16
#define CHUNK   (TOTAL / GSIZE)   // 2048 elements per block
#define WCHUNK  (CHUNK / NWAVE)   // 128 per wave (2 per lane)
#define ROWSPW  (GSIZE / NWAVE)   // 16 count-rows scanned per wave

// Mask of lanes whose ballot-encoded expert equals x (x in [0,64)).
// bb[bit] = __ballot of bit 'bit' of each lane's expert id (wave-uniform).
__device__ __forceinline__ unsigned long long expert_mask(
        const unsigned long long bb[6], int x) {
    unsigned long long m = ~0ULL;
#pragma unroll
    for (int bit = 0; bit < 6; bit++)
        m &= ((x >> bit) & 1) ? bb[bit] : ~bb[bit];
    return m;
}

// ---------------- Kernel A: per-block expert histogram ----------------------
// Lane-as-expert counting: lane i accumulates popcount of "expert==i" masks.
__global__ __launch_bounds__(BLOCK) void hist_kernel(const int* __restrict__ idx,
                                                     int* __restrict__ counts) {
    __shared__ int hist[NWAVE][NEXP];
    const int tid = threadIdx.x, lane = tid & 63, wave = tid >> 6;

    const int2 e2 = ((const int2*)idx)[blockIdx.x * (CHUNK / 2) + tid];  // coalesced 8B

    unsigned long long bb0[6], bb1[6];
#pragma unroll
    for (int bit = 0; bit < 6; bit++) {
        bb0[bit] = __ballot((e2.x >> bit) & 1);
        bb1[bit] = __ballot((e2.y >> bit) & 1);
    }
    hist[wave][lane] = __popcll(expert_mask(bb0, lane)) +
                       __popcll(expert_mask(bb1, lane));
    __syncthreads();
    if (tid < NEXP) {
        int s = 0;
#pragma unroll
        for (int w = 0; w < NWAVE; w++) s += hist[w][tid];
        counts[blockIdx.x * NEXP + tid] = s;
    }
}

// ---------------- Kernel B: offsets + stable scatter (register-only) --------
__global__ __launch_bounds__(BLOCK) void scatter_kernel(
        const float* __restrict__ scores,
        const int*   __restrict__ idx,
        const int*   __restrict__ counts,
        float*       __restrict__ out_scores,
        float*       __restrict__ out_tok,
        float*       __restrict__ out_cnt) {
    __shared__ int part_pre[NWAVE][NEXP];   // per-wave partial: counts in blocks < b
    __shared__ int part_tot[NWAVE][NEXP];   // per-wave partial: global totals
    __shared__ int wtot[NWAVE][NEXP];       // this block: per-wave expert counts
    __shared__ int exscan_pre[NEXP];        // expert ex-scan + this block's prefix

    const int tid = threadIdx.x, lane = tid & 63, wave = tid >> 6, b = blockIdx.x;
    const unsigned long long lt  = (1ULL << lane) - 1ULL;
    const unsigned long long own = 1ULL << lane;

    // --- element loads, issued early (coalesced 8B each) ---
    const int2   e2 = ((const int2*)idx)[b * (CHUNK / 2) + tid];
    const float2 s2 = ((const float2*)scores)[b * (CHUNK / 2) + tid];

    // --- counts scan: expert = lane, 16 rows per wave (independent L2 loads) ---
    int pre = 0, tot = 0;
    {
        const int r0 = wave * ROWSPW;
#pragma unroll
        for (int q = 0; q < ROWSPW; q++) {
            const int bb = r0 + q;
            const int c  = counts[bb * NEXP + lane];   // lane-coalesced row
            tot += c;
            pre += (bb < b) ? c : 0;
        }
    }
    part_pre[wave][lane] = pre;
    part_tot[wave][lane] = tot;

    // --- ballots + lane-as-expert masks (registers only) ---
    const int e0 = e2.x, e1 = e2.y;
    unsigned long long bb0[6], bb1[6];
#pragma unroll
    for (int bit = 0; bit < 6; bit++) {
        bb0[bit] = __ballot((e0 >> bit) & 1);
        bb1[bit] = __ballot((e1 >> bit) & 1);
    }
    const unsigned long long M0 = expert_mask(bb0, lane);  // lanes with slot-0 expert == lane
    const unsigned long long M1 = expert_mask(bb1, lane);  // lanes with slot-1 expert == lane
    wtot[wave][lane] = __popcll(M0) + __popcll(M1);        // this wave's count of expert 'lane'
    __syncthreads();

    // --- combine partials + expert exclusive scan (wave 0, shfl-based) ---
    if (wave == 0) {
        int p = 0, t = 0;
#pragma unroll
        for (int w = 0; w < NWAVE; w++) {
            p += part_pre[w][lane];
            t += part_tot[w][lane];
        }
        if (b == 0) out_cnt[lane] = (float)t;   // num_tokens_per_expert (fp32)
        int inc = t;                            // 64-lane inclusive scan
#pragma unroll
        for (int d = 1; d < 64; d <<= 1) {
            const int v = __shfl_up(inc, d, 64);
            if (lane >= d) inc += v;
        }
        exscan_pre[lane] = (inc - t) + p;       // exclusive scan + block prefix
    }
    __syncthreads();

    // --- per-lane (= per-expert) wave start offset, register-resident ---
    int base = exscan_pre[lane];
#pragma unroll
    for (int w = 0; w < NWAVE; w++)
        base += (w < wave) ? wtot[w][lane] : 0;

    // --- fetch cross-expert masks/offsets from the owning lane ---
    const unsigned long long own0 = __shfl(M0, e0, 64);   // M0(e0)
    const unsigned long long own1 = __shfl(M1, e1, 64);   // M1(e1)
    const unsigned long long c01  = __shfl(M1, e0, 64);   // M1(e0)
    const unsigned long long c10  = __shfl(M0, e1, 64);   // M0(e1)
    const int base0 = __shfl(base, e0, 64);
    const int base1 = __shfl(base, e1, 64);

    // stable in-wave ranks (flat order = 2*lane + sub)
    const int rank0 = __popcll(own0 & lt) + __popcll(c01 & lt);
    const int rank1 = __popcll(c10 & (lt | own)) + __popcll(own1 & lt);

    const int f0 = b * CHUNK + 2 * tid;        // flattened assignment index (sub 0)
    const int pos0 = base0 + rank0;
    const int pos1 = base1 + rank1;

    out_scores[pos0] = s2.x;
    out_scores[pos1] = s2.y;
    out_tok[pos0]    = (float)(f0 >> 3);        // /TOPK, exact in fp32 (<65536)
    out_tok[pos1]    = (float)((f0 + 1) >> 3);
}

extern "C" void kernel_launch(void* const* d_in, const int* in_sizes, int n_in,
                              void* d_out, int out_size, void* d_ws, size_t ws_size,
                              hipStream_t stream) {
    const float* top_scores = (const float*)d_in[0];
    const int*   sel_idx    = (const int*)d_in[1];
    float*       out        = (float*)d_out;
    int*         counts     = (int*)d_ws;   // GSIZE*NEXP ints = 64 KB

    // d_out layout: [scores_sorted (TOTAL)] [token_idx_sorted (TOTAL)] [counts (NEXP)]
    float* out_scores = out;
    float* out_tok    = out + TOTAL;
    float* out_cnt    = out + 2 * TOTAL;

    hist_kernel<<<GSIZE, BLOCK, 0, stream>>>(sel_idx, counts);
    scatter_kernel<<<GSIZE, BLOCK, 0, stream>>>(top_scores, sel_idx, counts,
                                                out_scores, out_tok, out_cnt);
}